// Round 1
// 699.155 us; speedup vs baseline: 1.0065x; 1.0065x over previous
//
#include <hip/hip_runtime.h>
#include <cstdint>
#include <cstddef>

// R1: async DMA staging (global_load_lds width=16, depth-1 double buffer) +
// raw s_barrier discipline (vmcnt drained ONLY at the consume point) +
// 3 blocks/CU occupancy. Theory: mg_kernel (~200us inferred) is
// gather-latency-bound vs ~90us HBM floor; overlap stage(g+1) DMA with
// MFMA/interp/merge/store of g.
//
// Problem constants (SharedMGEmbedder) — all float inputs FP32, output FP32.
// bf16 is used ONLY for the MFMA (t6 @ W) path; 2%-relative threshold allows it.
#define Bb 2
#define Vv 4
#define VTt 4
#define Ff 128
#define Ee 128
#define NHh 7
#define N6c 196608
#define N5c 49152
#define N4c 12288
#define PFc 32768
#define P5c 8192
#define P4c 2048
#define O5c 4
#define O4c 16
#define GRP 4   // pc4 groups per block (amortizes W-fragment loads, feeds pipeline)

typedef __attribute__((ext_vector_type(8))) short short8;
typedef __attribute__((ext_vector_type(4))) float f32x4;
typedef __attribute__((ext_vector_type(2))) float f32x2;
typedef unsigned short u16;

__device__ __forceinline__ u16 f2bf(float f){
  union { float f; unsigned int i; } c; c.f = f;
  unsigned int x = c.i;
  return (u16)((x + 0x7fffu + ((x >> 16) & 1u)) >> 16);  // RNE fp32->bf16
}

// Pre-swizzle W (fp32 [F,E]) into bf16 B-fragment order for mfma_f32_16x16x32_bf16:
// wsw[((nt*4+kk)*64+lane)*8 + j] = bf16( W[(kk*32+(lane>>4)*8+j)][nt*16+(lane&15)] )
__global__ void setup_kernel(const float* __restrict__ W, u16* __restrict__ wsw){
  int tid = blockIdx.x * 256 + threadIdx.x;
  if (tid < 16384){
    int j = tid & 7, lane = (tid >> 3) & 63, kk = (tid >> 9) & 3, nt = tid >> 11;
    int f = kk * 32 + (lane >> 4) * 8 + j;
    int e = nt * 16 + (lane & 15);
    wsw[tid] = f2bf(W[f * Ee + e]);
  }
}

// 16B async global->LDS DMA. LDS dest is wave-uniform base + lane*16 — our
// chunk ids are linear in tid, so per-lane dest == base + lane*16. Rows are
// therefore UNPADDED (stride 128 floats); interp reads are within-row so the
// old +4 pad was never needed on the read side.
__device__ __forceinline__ void gload_lds16(const float* g, float* l){
  __builtin_amdgcn_global_load_lds(
      (const __attribute__((address_space(1))) unsigned int*)g,
      (__attribute__((address_space(3))) unsigned int*)l, 16, 0, 0);
}

// Consume barrier: stage(g) DMA (vmcnt) must be complete and LDS writes (sW/sB)
// visible. Single asm so nothing is scheduled between wait and barrier.
#define BAR_CONSUME() asm volatile("s_waitcnt vmcnt(0) lgkmcnt(0)\n\ts_barrier" ::: "memory")
// LDS-only barrier: does NOT drain vmcnt, so the in-flight stage(g+1) DMA
// survives across it (this is the whole point vs __syncthreads()).
#define BAR_LDS()     asm volatile("s_waitcnt lgkmcnt(0)\n\ts_barrier" ::: "memory")

__launch_bounds__(256, 3)  // LDS (~44.8KB) caps at 3 blocks/CU; VGPR cap ~170
__global__ void mg_kernel(
    const float* __restrict__ t6, const float* __restrict__ t5, const float* __restrict__ t4,
    const float* __restrict__ rel5, const float* __restrict__ rel4,
    const float* __restrict__ m5, const float* __restrict__ m4,
    const int* __restrict__ vidx, const int* __restrict__ idx6,
    const int* __restrict__ nh5, const int* __restrict__ nh4,
    const u16* __restrict__ wsw, const float* __restrict__ bias,
    float* __restrict__ out)
{
  __shared__ float sT5[2][28 * 128];   // double-buffered, unpadded (DMA dest)
  __shared__ float sT4[2][7 * 128];
  __shared__ float sW5[16 * 8];
  __shared__ float sW4[16 * 8];
  __shared__ float sB[Ee];
  __shared__ float sOut[16 * 132];     // padded: acc-merge reads cross rows

  const int tid = threadIdx.x;
  const int lane = tid & 63;
  const int wid = tid >> 6;
  const int blk = blockIdx.x;
  const int bv = blk / (P4c / GRP);
  const int pbase = (blk % (P4c / GRP)) * GRP;
  const int v = bv % Vv, b = bv / Vv;
  const int vi = vidx[b * Vv + v];

  if (tid < Ee) sB[tid] = bias[tid];

  // Fire-and-forget staging of one pc4 group's t5/t4 neighbor rows into buf.
  auto stage = [&](int pp, int buf){
    float* d5 = sT5[buf];
    for (int k = tid; k < 896; k += 256){        // 28 rows x 32 chunks (t5)
      int row = k >> 5, c = k & 31;
      int gi = nh5[b * (P5c * NHh) + (pp * 4 + row / 7) * NHh + (row % 7)];
      gload_lds16(t5 + ((size_t)vi * N5c + gi) * Ff + c * 4, d5 + k * 4);
    }
    if (tid < 224){                              // 7 rows x 32 chunks (t4)
      int row = tid >> 5, c = tid & 31;
      int gi = nh4[b * (P4c * NHh) + pp * NHh + row];
      gload_lds16(t4 + ((size_t)vi * N4c + gi) * Ff + c * 4, sT4[buf] + tid * 4);
    }
  };

  stage(pbase, 0);   // prologue fill of buffer 0 (only non-overlapped stage)

  // persistent bf16 W fragments in registers (reused across GRP groups)
  short8 bfrag[2][4];
  const int ntb = wid * 2;
#pragma unroll
  for (int i = 0; i < 2; i++)
#pragma unroll
    for (int kk = 0; kk < 4; kk++)
      bfrag[i][kk] = *(const short8*)(wsw + (((ntb + i) * 4 + kk) * 64 + lane) * 8);

  const int m = lane & 15, q = lane >> 4;

  for (int g = 0; g < GRP; g++){
    const int pc4 = pbase + g;
    const int cur = g & 1;
    const float* sT5c = sT5[cur];
    const float* sT4c = sT4[cur];

    // ---- interpolation weights (32 threads; latency overlaps stage(g) drain)
    // sW write-after-read vs interp(g-1): separated by >=2 barriers below.
    if (tid >= 128 && tid < 144){
      int t = tid - 128;                               // o4 = t
      float raw[7], s = 0.f;
#pragma unroll
      for (int n = 0; n < 7; n++){
        float rd = rel4[((b * P4c + pc4) * O4c + t) * NHh + n]
                 + m4[(b * P4c + pc4) * NHh + n] * 1e10f;
        raw[n] = 1.0f / (1e-20f + rd); s += raw[n];
      }
      float inv = 1.0f / s;
#pragma unroll
      for (int n = 0; n < 7; n++) sW4[t * 8 + n] = raw[n] * inv;
    } else if (tid >= 144 && tid < 160){
      int t = tid - 144;                               // pc5 = pc4*4 + t/4, o5 = t%4
      int pc5 = pc4 * 4 + (t >> 2), o = t & 3;
      float raw[7], s = 0.f;
#pragma unroll
      for (int n = 0; n < 7; n++){
        float rd = rel5[((b * P5c + pc5) * O5c + o) * NHh + n]
                 + m5[(b * P5c + pc5) * NHh + n] * 1e10f;
        raw[n] = 1.0f / (1e-20f + rd); s += raw[n];
      }
      float inv = 1.0f / s;
#pragma unroll
      for (int n = 0; n < 7; n++) sW5[t * 8 + n] = raw[n] * inv;
    }

    // ---- A fragments: fp32 rows from t6, convert to bf16 in-register ----
    int rown = idx6[b * PFc + pc4 * 16 + m];
    const float* arow = t6 + ((size_t)vi * N6c + rown) * Ff + q * 8;
    short8 af[4];
#pragma unroll
    for (int kk = 0; kk < 4; kk++){
      f32x4 lo = *(const f32x4*)(arow + kk * 32);
      f32x4 hi = *(const f32x4*)(arow + kk * 32 + 4);
      short8 cv;
#pragma unroll
      for (int j = 0; j < 4; j++){
        cv[j]     = (short)f2bf(lo[j]);
        cv[j + 4] = (short)f2bf(hi[j]);
      }
      af[kk] = cv;
    }

    BAR_CONSUME();   // stage(g) landed in sT[cur]; sW/sB visible to all waves

    // Prefetch next group into the other buffer. Safe: interp(g-1) finished
    // reading sT[cur^1] before its post-interp barrier, >=2 barriers ago.
    // Drained only at next iteration's BAR_CONSUME — stays in flight across
    // the BAR_LDS barriers below.
    if (g + 1 < GRP) stage(pc4 + 1, cur ^ 1);

    // ---- MFMA: 16 rows x 32 cols per wave (waves split the 128 cols) ----
    f32x4 acc0 = {0.f, 0.f, 0.f, 0.f}, acc1 = {0.f, 0.f, 0.f, 0.f};
#pragma unroll
    for (int kk = 0; kk < 4; kk++){
      acc0 = __builtin_amdgcn_mfma_f32_16x16x32_bf16(af[kk], bfrag[0][kk], acc0, 0, 0, 0);
      acc1 = __builtin_amdgcn_mfma_f32_16x16x32_bf16(af[kk], bfrag[1][kk], acc1, 0, 0, 0);
    }

    // ---- interp + bias into fp32 LDS tile (float2 within-row reads) ----
    for (int k = tid; k < 1024; k += 256){
      int t = k >> 6, ep = (k & 63) * 2;
      float v0 = sB[ep], v1 = sB[ep + 1];
      const float* w4p = sW4 + t * 8;
      const float* w5p = sW5 + t * 8;
      const float* b4 = sT4c + ep;
      const float* b5 = sT5c + (t >> 2) * 7 * 128 + ep;
#pragma unroll
      for (int n = 0; n < 7; n++){
        f32x2 a4 = *(const f32x2*)(b4 + n * 128);
        float w4 = w4p[n];
        v0 += w4 * a4[0]; v1 += w4 * a4[1];
        f32x2 a5 = *(const f32x2*)(b5 + n * 128);
        float w5 = w5p[n];
        v0 += w5 * a5[0]; v1 += w5 * a5[1];
      }
      sOut[t * 132 + ep]     = v0;
      sOut[t * 132 + ep + 1] = v1;
    }

    BAR_LDS();       // interp tile ready (vmcnt NOT drained)

    // ---- add MFMA accumulators (C/D: col=lane&15, row=q*4+reg) ----
    {
      int col = wid * 32 + m;
#pragma unroll
      for (int r = 0; r < 4; r++){
        int row = q * 4 + r;
        sOut[row * 132 + col]      += acc0[r];
        sOut[row * 132 + col + 16] += acc1[r];
      }
    }

    BAR_LDS();       // acc merged (vmcnt NOT drained)

    // ---- coalesced nontemporal fp32 store: 16 rows x 512B ----
    {
      int t = tid >> 4, c = (tid & 15) * 8;
      const float* sp = sOut + t * 132 + c;
      size_t obase = (((size_t)bv) * PFc + (size_t)pc4 * 16 + t) * Ee + c;
      f32x4 w0 = *(const f32x4*)(sp);
      f32x4 w1 = *(const f32x4*)(sp + 4);
      __builtin_nontemporal_store(w0, (f32x4*)(out + obase));
      __builtin_nontemporal_store(w1, (f32x4*)(out + obase + 4));
    }
    // sOut reads are consumed into regs before the stores issue, and every
    // thread crosses next iteration's BAR_CONSUME before interp(g+1) writes
    // sOut — no cross-iter race. Stores drain at next BAR_CONSUME (harmless).
  }
}

extern "C" void kernel_launch(void* const* d_in, const int* in_sizes, int n_in,
                              void* d_out, int out_size, void* d_ws, size_t ws_size,
                              hipStream_t stream){
  const float* t6   = (const float*)d_in[0];
  const float* t5   = (const float*)d_in[1];
  const float* t4   = (const float*)d_in[2];
  const float* W    = (const float*)d_in[3];
  const float* bias = (const float*)d_in[4];
  const float* rel5 = (const float*)d_in[5];
  const float* rel4 = (const float*)d_in[6];
  const float* m5   = (const float*)d_in[7];
  const float* m4   = (const float*)d_in[8];
  const int* vidx = (const int*)d_in[9];
  const int* idx6 = (const int*)d_in[10];
  const int* nh5  = (const int*)d_in[11];
  const int* nh4  = (const int*)d_in[12];

  u16* wsw = (u16*)d_ws;   // 32768 B swizzled bf16 W

  setup_kernel<<<64, 256, 0, stream>>>(W, wsw);

  int grid = (Bb * Vv * P4c) / GRP;                // 4096 blocks x 256 threads
  mg_kernel<<<grid, 256, 0, stream>>>(t6, t5, t4, rel5, rel4, m5, m4,
                                      vidx, idx6, nh5, nh4, wsw, bias,
                                      (float*)d_out);
}